// Round 12
// baseline (542.798 us; speedup 1.0000x reference)
//
#include <hip/hip_runtime.h>
#include <cstdint>

constexpr int B    = 256;
constexpr int S    = 33;
constexpr int D    = 42;
constexpr int H    = 128;
constexpr int HFF  = 256;
constexpr int T    = 20;
constexpr int NSTEP = S - 1;   // 32
constexpr int DP   = D / 2;    // 21 f16 d-pairs
constexpr int ADW  = 8192;     // dwords per (s,b) A-slice (e5m2, 32 KB)
constexpr int CH   = 16;       // steps per chunk (A chunk = 128 MiB)
constexpr int NCH  = NSTEP / CH;  // 2 chunks
#define BN_SCALE 0.9999950000374997f

typedef _Float16 h2v __attribute__((ext_vector_type(2)));
typedef _Float16 f16x8 __attribute__((ext_vector_type(8)));
typedef float    f32x4 __attribute__((ext_vector_type(4)));
union UH2 { uint32_t u; h2v h; };

__device__ __forceinline__ float fdot2u(uint32_t a, uint32_t b, float c) {
    UH2 x, y; x.u = a; y.u = b;
    return __builtin_amdgcn_fdot2(x.h, y.h, c, false);
}
__device__ __forceinline__ uint32_t packh2(float a, float b) {
    UH2 u; u.h = h2v{(_Float16)a, (_Float16)b}; return u.u;
}
__device__ __forceinline__ float gelu_exact(float x) {
    return 0.5f * x * (1.0f + erff(x * 0.70710678118654752f));
}
// fast gelu for the hot scan (err ~3e-4, far under the 1e-2 threshold)
__device__ __forceinline__ float gelu_fast(float x) {
    float inner = x * (1.0f + 0.044715f * x * x);
    float E = __expf(1.5957691216f * inner);
    return x * E * __frcp_rn(E + 1.0f);
}
// A-staging swizzle (uint4 index): column ^= (row>>4)<<1 so that L3's
// intra-wave (h = t>>2, g = t&3) reads land 2-way max on LDS banks.
__device__ __forceinline__ int aswz(int idx) {
    return (idx & ~31) | ((idx & 31) ^ (((idx >> 9) & 3) << 1));
}

// ---------------------------------------------------------------------------
// Merged one-time pack + prep (r11, unchanged).
// Blocks [0, 4096): pack role (wcol half-K layout + wp MFMA A-operand).
// Blocks [4096, 4096+B): prep role (encoder z0, padded dxdt, bd3g, dt).
// ---------------------------------------------------------------------------
__global__ void __launch_bounds__(256) packprep_kernel(
    const float* __restrict__ w0, const float* __restrict__ w1,
    const float* __restrict__ w2, const float* __restrict__ w3,
    uint32_t* __restrict__ wcol, uint32_t* __restrict__ wp,
    const float* __restrict__ path, const float* __restrict__ ts,
    const float* __restrict__ ew1, const float* __restrict__ eb1,
    const float* __restrict__ eg1, const float* __restrict__ ebe1,
    const float* __restrict__ ew2, const float* __restrict__ eb2,
    const float* __restrict__ eg2, const float* __restrict__ ebe2,
    const float* __restrict__ b3,
    float* __restrict__ zbuf, uint32_t* __restrict__ dxp,
    float* __restrict__ bd3g, float* __restrict__ dtb) {
    int tid = threadIdx.x;
    if (blockIdx.x < 4096) {
        // ---------------- pack role ----------------
        int idx = blockIdx.x * 256 + tid;
        if (idx < 160 * 512) {
            int r = idx >> 9, t = idx & 511;
            int j = t >> 1, half = t & 1;
            float a, bb;
            if (r < 32)      { int ip = half * 32 + r;      a = w0[(2*ip)*HFF + j]; bb = w0[(2*ip+1)*HFF + j]; }
            else if (r < 96) { int ip = half * 64 + (r-32); a = w1[(2*ip)*HFF + j]; bb = w1[(2*ip+1)*HFF + j]; }
            else             { int ip = half * 64 + (r-96); a = w2[(2*ip)*HFF + j]; bb = w2[(2*ip+1)*HFF + j]; }
            wcol[idx] = packh2(a, bb);
        }
        if (idx < 32768 * 32) {
            int m = idx >> 5, dd = (idx & 31) * 2;
            int e = 4 * (m >> 9) + (m & 3);
            int h = (m >> 2) & 127;
            const float* row = w3 + (size_t)e * (H * D) + h * D;
            float a = (dd     < D) ? row[dd]     : 0.f;
            float b = (dd + 1 < D) ? row[dd + 1] : 0.f;
            wp[idx] = packh2(a, b);
        }
        return;
    }
    // ---------------- prep role (256 threads) ----------------
    __shared__ float x0[D], hb[H], dxs[NSTEP][D];
    int b = blockIdx.x - 4096;
    if (tid < D) x0[tid] = path[b * S * D + tid];
    __syncthreads();
    if (tid < H) {
        float acc = eb1[tid];
        for (int d = 0; d < D; ++d) acc += x0[d] * ew1[d * H + tid];
        hb[tid] = gelu_exact(acc * (eg1[tid] * BN_SCALE) + ebe1[tid]);
    }
    __syncthreads();
    if (tid < H) {
        float acc = eb2[tid];
        for (int i = 0; i < H; ++i) acc += hb[i] * ew2[i * H + tid];
        zbuf[b * H + tid] = acc * (eg2[tid] * BN_SCALE) + ebe2[tid];
    }
    for (int idx = tid; idx < NSTEP * 32; idx += 256) {
        int s = idx >> 5, j2 = idx & 31;
        uint32_t val = 0;
        if (j2 < DP) {
            float dtv = ts[s + 1] - ts[s];
            int base = b * S * D + s * D + 2 * j2;
            float v0 = (path[base + D] - path[base]) / dtv;
            float v1 = (path[base + D + 1] - path[base + 1]) / dtv;
            dxs[s][2 * j2] = v0; dxs[s][2 * j2 + 1] = v1;
            val = packh2(v0, v1);
        }
        dxp[((size_t)(s * B + b)) * 32 + j2] = val;
    }
    __syncthreads();
    if (tid < H) {
        for (int s = 0; s < NSTEP; ++s) {
            float a = 0.f;
            for (int d = 0; d < D; ++d) a += b3[tid * D + d] * dxs[s][d];
            bd3g[(size_t)(s * B + b) * H + tid] = a;
        }
    }
    if (b == 0 && tid < NSTEP) dtb[tid] = ts[tid + 1] - ts[tid];
}

// ---------------------------------------------------------------------------
// MFMA A-phase (round-9 version, unchanged): LDS-transpose coalesced stores.
// ---------------------------------------------------------------------------
__global__ void __launch_bounds__(256) amm_kernel(
    const uint32_t* __restrict__ wp, const uint32_t* __restrict__ dxp,
    uint32_t* __restrict__ Ach, int s0) {
    __shared__ __align__(16) uint32_t xpose[4][16 * 36];   // 9.2 KB
    int t = threadIdx.x;
    int l = t & 63, wid = t >> 6;
    int mg = (blockIdx.x & 63) * 4 + wid;        // 0..255
    int sg = blockIdx.x >> 6;                    // 0..31
    int lr = l & 15, lk = l >> 4;
    const char* wpB = (const char*)wp;
    const char* dxB = (const char*)dxp + (size_t)s0 * B * 128;
    char* asB = (char*)Ach;
    uint32_t* xp = xpose[wid];
    f16x8 af0[8], af1[8];
#pragma unroll
    for (int mi = 0; mi < 8; ++mi) {
        const f16x8* p = (const f16x8*)(wpB + ((size_t)(mg * 8 + mi) * 16 + lr) * 128 + lk * 16);
        af0[mi] = p[0]; af1[mi] = p[4];          // d 0..31, d 32..63
    }
#pragma unroll
    for (int si = 0; si < 8; ++si) {
        int q = sg * 128 + si * 16 + lr;         // chunk-local slice (this lane's C col)
#pragma unroll
        for (int mi = 0; mi < 8; ++mi) {
            const f16x8* bp = (const f16x8*)(dxB + (size_t)q * 128 + lk * 16);
            f16x8 b0 = bp[0], b1 = bp[4];
            f32x4 acc = {0.f, 0.f, 0.f, 0.f};
            acc = __builtin_amdgcn_mfma_f32_16x16x32_f16(af0[mi], b0, acc, 0, 0, 0);
            acc = __builtin_amdgcn_mfma_f32_16x16x32_f16(af1[mi], b1, acc, 0, 0, 0);
            uint32_t P0 = packh2(acc[0], acc[1]) + 0x00800080u;
            uint32_t P1 = packh2(acc[2], acc[3]) + 0x00800080u;
            uint32_t Q = __builtin_amdgcn_perm(P1, P0, 0x07050301u);
            xp[lr * 36 + lk + 4 * mi] = Q;
        }
        __syncthreads();
        {
            int qr = l >> 2, seg = l & 3;
            const uint4* src = (const uint4*)(xp + qr * 36 + seg * 8);
            uint4 v0 = src[0], v1 = src[1];
            int qout = sg * 128 + si * 16 + qr;
            char* outB = asB + (size_t)qout * 32768 + mg * 128 + seg * 32;
            *(uint4*)outB = v0;
            *(uint4*)(outB + 16) = v1;
        }
        __syncthreads();
    }
}

// ---------------------------------------------------------------------------
// Scan (per 16-step chunk): frozen r7/r9 main loop (158.6 us, VGPR 120-124,
// no spill; 6 alternative structures all regressed — r1-r4, r6, r8, r10).
// do_att epilogue (last chunk): att + FULL DECODER, writing out directly.
//  * epilogue LDS aliased onto dead ABUF[0] (no LDS growth vs r9).
//  * quarter-dot reads rotated (ii = i0 + ((i+8g)&31)) — r11's 131072
//    bank conflicts came from stride-32-dword (same-bank) quarter reads.
//  * dec: wave wid handles decoder t = wid, wid+8, wid+16; no barriers in
//    the unequal-trip loop (per-wave LDS region; intra-wave ds order).
// ---------------------------------------------------------------------------
__global__ void __launch_bounds__(512, 1)
__attribute__((amdgpu_waves_per_eu(2, 8)))
scan_kernel(
    const uint32_t* __restrict__ wcol, const uint32_t* __restrict__ Ach,
    const float* __restrict__ vb0, const float* __restrict__ vg0, const float* __restrict__ vbe0,
    const float* __restrict__ vb1, const float* __restrict__ vg1, const float* __restrict__ vbe1,
    const float* __restrict__ vb2, const float* __restrict__ vg2, const float* __restrict__ vbe2,
    const float* __restrict__ bd3g, const float* __restrict__ dtb,
    float* __restrict__ zbuf, int s0, int do_att,
    const float* __restrict__ wv, const float* __restrict__ bv,
    const float* __restrict__ wo, const float* __restrict__ bo,
    const float* __restrict__ dw1, const float* __restrict__ db1,
    const float* __restrict__ dw2, const float* __restrict__ db2,
    const float* __restrict__ dw3, const float* __restrict__ db3,
    float* __restrict__ out) {
    __shared__ __align__(16) uint32_t ABUF[2][ADW];            // 64 KB
    __shared__ __align__(16) uint32_t zzPd[72];                // half*36 + r
    __shared__ __align__(16) uint32_t yA[136], yB[136], yC[136]; // half*68 + r
    int t = threadIdx.x, b = blockIdx.x;
    int j = t >> 1, half = t & 1;                     // MLP role
    int h = t >> 2, g = t & 3;                        // L3/state role
    int hswz = h ^ (g << 3);                          // swizzled A column
    uint32_t w0h[32], w1h[64], w2h[64];
#pragma unroll
    for (int r = 0; r < 32; ++r) w0h[r] = wcol[r * 512 + t];
#pragma unroll
    for (int r = 0; r < 64; ++r) w1h[r] = wcol[(32 + r) * 512 + t];
#pragma unroll
    for (int r = 0; r < 64; ++r) w2h[r] = wcol[(96 + r) * 512 + t];
    // folded BN: out = gelu(p*cs + co)
    float c0s = vg0[j] * BN_SCALE, c0o = vb0[j] * c0s + vbe0[j];
    float c1s = vg1[j] * BN_SCALE, c1o = vb1[j] * c1s + vbe1[j];
    float c2s = vg2[j] * BN_SCALE, c2o = vb2[j] * c2s + vbe2[j];
    float zf = zbuf[b * H + h];
    // prologue: stage A for local step 0 (swizzled)
    {
        const uint4* Ag = (const uint4*)(Ach + (size_t)b * ADW);
        uint4 a0 = Ag[t], a1 = Ag[512 + t], a2 = Ag[1024 + t], a3 = Ag[1536 + t];
        uint4* Ad = (uint4*)ABUF[0];
        Ad[aswz(t)] = a0; Ad[aswz(512 + t)] = a1;
        Ad[aswz(1024 + t)] = a2; Ad[aswz(1536 + t)] = a3;
    }
    {
        float zhi = __shfl_down(zf, 4, 64);
        if ((t & 7) == 0) {
            int ip = t >> 3;
            zzPd[(ip >> 5) * 36 + (ip & 31)] = packh2(zf, zhi);
        }
    }
    __syncthreads();

    for (int sl = 0; sl < CH; ++sl) {
        int s = s0 + sl;
        float hstep = dtb[s];
        float bd3 = bd3g[(size_t)(s * B + b) * H + h];
        // prefetch next step's A into registers (in flight across the step)
        uint4 pf0, pf1, pf2, pf3;
        {
            int sn = (sl + 1 < CH) ? sl + 1 : sl;
            const uint4* Ag = (const uint4*)(Ach + (size_t)(sn * B + b) * ADW);
            pf0 = Ag[t]; pf1 = Ag[512 + t]; pf2 = Ag[1024 + t]; pf3 = Ag[1536 + t];
        }
        const uint32_t* AL = ABUF[sl & 1];
        float ksum = 0.f, kcur = 0.f;
        for (int r = 0; r < 4; ++r) {
            // ---- L0: 128 -> 256 (half-K per lane, 4 accumulators) ----
            {
                float pa = 0.f, pb = 0.f, pc = 0.f, pd = 0.f;
                const uint4* zq = (const uint4*)(zzPd + half * 36);
#pragma unroll
                for (int u4 = 0; u4 < 8; ++u4) {
                    uint4 zv = zq[u4];
                    pa = fdot2u(w0h[4*u4+0], zv.x, pa); pb = fdot2u(w0h[4*u4+1], zv.y, pb);
                    pc = fdot2u(w0h[4*u4+2], zv.z, pc); pd = fdot2u(w0h[4*u4+3], zv.w, pd);
                }
                float p = (pa + pb) + (pc + pd);
                p += __shfl_xor(p, 1, 64);
                float v = gelu_fast(p * c0s + c0o);
                float vhi = __shfl_down(v, 2, 64);
                if ((t & 3) == 0) {
                    int ip = t >> 2;
                    yA[(ip >> 6) * 68 + (ip & 63)] = packh2(v, vhi);
                }
            }
            __syncthreads();
            // ---- L1: 256 -> 256 (4 accumulators) ----
            {
                float pa = 0.f, pb = 0.f, pc = 0.f, pd = 0.f;
                const uint4* yq = (const uint4*)(yA + half * 68);
#pragma unroll
                for (int u4 = 0; u4 < 16; ++u4) {
                    uint4 yv = yq[u4];
                    pa = fdot2u(w1h[4*u4+0], yv.x, pa); pb = fdot2u(w1h[4*u4+1], yv.y, pb);
                    pc = fdot2u(w1h[4*u4+2], yv.z, pc); pd = fdot2u(w1h[4*u4+3], yv.w, pd);
                }
                float p = (pa + pb) + (pc + pd);
                p += __shfl_xor(p, 1, 64);
                float v = gelu_fast(p * c1s + c1o);
                float vhi = __shfl_down(v, 2, 64);
                if ((t & 3) == 0) {
                    int ip = t >> 2;
                    yB[(ip >> 6) * 68 + (ip & 63)] = packh2(v, vhi);
                }
            }
            __syncthreads();
            // ---- L2: 256 -> 256 (4 accumulators) ----
            {
                float pa = 0.f, pb = 0.f, pc = 0.f, pd = 0.f;
                const uint4* yq = (const uint4*)(yB + half * 68);
#pragma unroll
                for (int u4 = 0; u4 < 16; ++u4) {
                    uint4 yv = yq[u4];
                    pa = fdot2u(w2h[4*u4+0], yv.x, pa); pb = fdot2u(w2h[4*u4+1], yv.y, pb);
                    pc = fdot2u(w2h[4*u4+2], yv.z, pc); pd = fdot2u(w2h[4*u4+3], yv.w, pd);
                }
                float p = (pa + pb) + (pc + pd);
                p += __shfl_xor(p, 1, 64);
                float v = gelu_fast(p * c2s + c2o);
                float vhi = __shfl_down(v, 2, 64);
                if ((t & 3) == 0) {
                    int ip = t >> 2;
                    yC[(ip >> 6) * 68 + (ip & 63)] = packh2(v, vhi);
                }
            }
            __syncthreads();
            // ---- L3 + state (fused): lane (h = t>>2, g = t&3) covers
            //      k-quads g*16..g*16+15; intra-wave reduce over g. ----
            {
                float pA = 0.f, pB = 0.f, pC = 0.f, pD = 0.f;
                int ybase = (g >> 1) * 68 + (g & 1) * 32;
                const uint4* yq = (const uint4*)(yC + ybase);
#pragma unroll
                for (int kk = 0; kk < 8; ++kk) {
                    uint4 yv = yq[kk];
                    int k0 = g * 16 + 2 * kk;
                    uint32_t Qa = AL[k0 * 128 + hswz];
                    uint32_t Qb = AL[(k0 + 1) * 128 + hswz];
                    pA = fdot2u(__builtin_amdgcn_perm(0u, Qa, 0x010C000Cu), yv.x, pA);
                    pB = fdot2u(__builtin_amdgcn_perm(0u, Qa, 0x030C020Cu), yv.y, pB);
                    pC = fdot2u(__builtin_amdgcn_perm(0u, Qb, 0x010C000Cu), yv.z, pC);
                    pD = fdot2u(__builtin_amdgcn_perm(0u, Qb, 0x030C020Cu), yv.w, pD);
                }
                float ptot = (pA + pB) + (pC + pD);
                ptot += __shfl_xor(ptot, 1, 64);
                ptot += __shfl_xor(ptot, 2, 64);
                kcur = bd3 + ptot;                    // redundant across g-lanes
                float wsm = (r == 1 || r == 2) ? 2.f : 1.f;
                ksum += wsm * kcur;
                float zz;
                if (r < 3) {
                    float cin = (r == 2) ? 1.f : 0.5f;
                    zz = zf + cin * hstep * kcur;
                } else {
                    zf += hstep * (1.f / 6.f) * ksum;
                    zz = zf;
                }
                float zhi = __shfl_down(zz, 4, 64);
                if ((t & 7) == 0) {
                    int ip = t >> 3;
                    zzPd[(ip >> 5) * 36 + (ip & 31)] = packh2(zz, zhi);
                }
            }
            if (r == 3) {  // stage prefetched A into the other buffer (swizzled)
                uint4* Ad = (uint4*)ABUF[(sl + 1) & 1];
                Ad[aswz(t)] = pf0; Ad[aswz(512 + t)] = pf1;
                Ad[aswz(1024 + t)] = pf2; Ad[aswz(1536 + t)] = pf3;
            }
            __syncthreads();
        }
    }
    if ((t & 3) == 0) zbuf[b * H + h] = zf;
    if (do_att) {
        // LDS reuse: ABUF[0] is dead after the main loop (final AL=ABUF[1]).
        float* zfl  = (float*)ABUF[0];       // [128]
        float* vv   = zfl + 128;             // [128]
        float* attl = zfl + 256;             // [128]
        float* h1l  = zfl + 384;             // [8][64]
        if ((t & 3) == 0) zfl[h] = zf;
        __syncthreads();
        // attended layer 1: vv[h] = bv[h] + sum_i zfl[i]*wv[i*H+h].
        // Rotated quarter iteration: banks i+8g -> conflict-free (r11 had
        // 131072 conflicts from stride-32-dword same-bank reads).
        {
            float acc = 0.f;
            int i0 = 32 * g;
#pragma unroll 8
            for (int i = 0; i < 32; ++i) {
                int ii = i0 + ((i + 8 * g) & 31);
                acc += zfl[ii] * wv[ii * H + h];
            }
            acc += __shfl_xor(acc, 1, 64);
            acc += __shfl_xor(acc, 2, 64);
            if (g == 0) vv[h] = acc + bv[h];
        }
        __syncthreads();
        // attended layer 2: attl[h] = bo[h] + sum_i vv[i]*wo[i*H+h]
        {
            float acc = 0.f;
            int i0 = 32 * g;
#pragma unroll 8
            for (int i = 0; i < 32; ++i) {
                int ii = i0 + ((i + 8 * g) & 31);
                acc += vv[ii] * wo[ii * H + h];
            }
            acc += __shfl_xor(acc, 1, 64);
            acc += __shfl_xor(acc, 2, 64);
            if (g == 0) attl[h] = acc + bo[h];
        }
        __syncthreads();
        // decoder: wave wid handles t = wid, wid+8, wid+16 (<T).
        // No barriers below (unequal trip counts across waves).
        {
            int wid = t >> 6, l = t & 63;
            float* h1w = h1l + wid * 64;
            for (int tt = wid; tt < T; tt += 8) {
                float a1 = db1[tt * 64 + l];
                const float* w1p = dw1 + (size_t)tt * H * 64 + l;
#pragma unroll 8
                for (int i = 0; i < H; ++i) a1 += attl[i] * w1p[i * 64];
                h1w[l] = gelu_exact(a1);
                float v = 0.f;
                if (l < 32) {
                    float a2 = db2[tt * 32 + l];
                    const float* w2p = dw2 + (size_t)tt * 64 * 32 + l;
#pragma unroll 8
                    for (int i = 0; i < 64; ++i) a2 += h1w[i] * w2p[i * 32];
                    v = gelu_exact(a2) * dw3[tt * 32 + l];
                }
#pragma unroll
                for (int off = 16; off >= 1; off >>= 1) v += __shfl_down(v, off, 64);
                if (l == 0) out[b * T + tt] = 1.f / (1.f + expf(-(v + db3[tt])));
            }
        }
    }
}

// ---------------------------------------------------------------------------
extern "C" void kernel_launch(void* const* d_in, const int* in_sizes, int n_in,
                              void* d_out, int out_size, void* d_ws, size_t ws_size,
                              hipStream_t stream) {
    const float* path = (const float*)d_in[0];
    const float* ts   = (const float*)d_in[1];
    const float* ew1  = (const float*)d_in[2];
    const float* eb1  = (const float*)d_in[3];
    const float* eg1  = (const float*)d_in[4];
    const float* ebe1 = (const float*)d_in[5];
    const float* ew2  = (const float*)d_in[6];
    const float* eb2  = (const float*)d_in[7];
    const float* eg2  = (const float*)d_in[8];
    const float* ebe2 = (const float*)d_in[9];
    const float* vw0  = (const float*)d_in[10];
    const float* vb0  = (const float*)d_in[11];
    const float* vg0  = (const float*)d_in[12];
    const float* vbe0 = (const float*)d_in[13];
    const float* vw1  = (const float*)d_in[14];
    const float* vb1  = (const float*)d_in[15];
    const float* vg1  = (const float*)d_in[16];
    const float* vbe1 = (const float*)d_in[17];
    const float* vw2  = (const float*)d_in[18];
    const float* vb2  = (const float*)d_in[19];
    const float* vg2  = (const float*)d_in[20];
    const float* vbe2 = (const float*)d_in[21];
    const float* vw3  = (const float*)d_in[22];
    const float* vb3  = (const float*)d_in[23];
    const float* wv   = (const float*)d_in[24];
    const float* bv   = (const float*)d_in[25];
    const float* wo   = (const float*)d_in[26];
    const float* bo   = (const float*)d_in[27];
    const float* dw1  = (const float*)d_in[28];
    const float* db1  = (const float*)d_in[29];
    const float* dw2  = (const float*)d_in[30];
    const float* db2  = (const float*)d_in[31];
    const float* dw3  = (const float*)d_in[32];
    const float* db3  = (const float*)d_in[33];

    char* ws = (char*)d_ws;
    size_t off = 0;
    auto take = [&](size_t bytes) { char* p = ws + off; off += (bytes + 255) & ~(size_t)255; return p; };
    uint32_t* Ach   = (uint32_t*)take((size_t)CH * B * ADW * 4);    // 128 MiB
    uint32_t* dxp   = (uint32_t*)take((size_t)NSTEP * B * 32 * 4);  // 1 MiB (padded rows)
    float*    bd3g  = (float*)take((size_t)NSTEP * B * H * 4);      // 4 MiB
    float*    dtb   = (float*)take(NSTEP * 4);
    float*    zbuf  = (float*)take((size_t)B * H * 4);
    uint32_t* wcol  = (uint32_t*)take((size_t)160 * 512 * 4);       // 320 KB
    uint32_t* wp    = (uint32_t*)take((size_t)32768 * 32 * 4);      // 4 MiB

    packprep_kernel<<<4096 + B, 256, 0, stream>>>(
        vw0, vw1, vw2, vw3, wcol, wp,
        path, ts, ew1, eb1, eg1, ebe1, ew2, eb2, eg2, ebe2, vb3,
        zbuf, dxp, bd3g, dtb);
    for (int c = 0; c < NCH; ++c) {
        amm_kernel<<<2048, 256, 0, stream>>>(wp, dxp, Ach, c * CH);
        scan_kernel<<<B, 512, 0, stream>>>(wcol, Ach,
                                           vb0, vg0, vbe0, vb1, vg1, vbe1, vb2, vg2, vbe2,
                                           bd3g, dtb, zbuf, c * CH,
                                           (c == NCH - 1) ? 1 : 0,
                                           wv, bv, wo, bo,
                                           dw1, db1, dw2, db2, dw3, db3,
                                           (float*)d_out);
    }
}

// Round 13
// 530.963 us; speedup vs baseline: 1.0223x; 1.0223x over previous
//
#include <hip/hip_runtime.h>
#include <cstdint>

constexpr int B    = 256;
constexpr int S    = 33;
constexpr int D    = 42;
constexpr int H    = 128;
constexpr int HFF  = 256;
constexpr int T    = 20;
constexpr int NSTEP = S - 1;   // 32
constexpr int DP   = D / 2;    // 21 f16 d-pairs
constexpr int ADW  = 8192;     // dwords per (s,b) A-slice (e5m2, 32 KB)
constexpr int CH   = 16;       // steps per chunk (A chunk = 128 MiB)
constexpr int NCH  = NSTEP / CH;  // 2 chunks
#define BN_SCALE 0.9999950000374997f

typedef _Float16 h2v __attribute__((ext_vector_type(2)));
typedef _Float16 f16x8 __attribute__((ext_vector_type(8)));
typedef float    f32x4 __attribute__((ext_vector_type(4)));
union UH2 { uint32_t u; h2v h; };

__device__ __forceinline__ float fdot2u(uint32_t a, uint32_t b, float c) {
    UH2 x, y; x.u = a; y.u = b;
    return __builtin_amdgcn_fdot2(x.h, y.h, c, false);
}
__device__ __forceinline__ uint32_t packh2(float a, float b) {
    UH2 u; u.h = h2v{(_Float16)a, (_Float16)b}; return u.u;
}
__device__ __forceinline__ float gelu_exact(float x) {
    return 0.5f * x * (1.0f + erff(x * 0.70710678118654752f));
}
// fast gelu for the hot scan (err ~3e-4, far under the 1e-2 threshold)
__device__ __forceinline__ float gelu_fast(float x) {
    float inner = x * (1.0f + 0.044715f * x * x);
    float E = __expf(1.5957691216f * inner);
    return x * E * __frcp_rn(E + 1.0f);
}
// A-staging swizzle (uint4 index): column ^= (row>>4)<<1 so that L3's
// intra-wave (h = t>>2, g = t&3) reads land 2-way max on LDS banks.
__device__ __forceinline__ int aswz(int idx) {
    return (idx & ~31) | ((idx & 31) ^ (((idx >> 9) & 3) << 1));
}

// ---------------------------------------------------------------------------
// Merged one-time pack + prep (r11, unchanged).
// Blocks [0, 4096): pack role (wcol half-K layout + wp MFMA A-operand).
// Blocks [4096, 4096+B): prep role (encoder z0, padded dxdt, bd3g, dt).
// ---------------------------------------------------------------------------
__global__ void __launch_bounds__(256) packprep_kernel(
    const float* __restrict__ w0, const float* __restrict__ w1,
    const float* __restrict__ w2, const float* __restrict__ w3,
    uint32_t* __restrict__ wcol, uint32_t* __restrict__ wp,
    const float* __restrict__ path, const float* __restrict__ ts,
    const float* __restrict__ ew1, const float* __restrict__ eb1,
    const float* __restrict__ eg1, const float* __restrict__ ebe1,
    const float* __restrict__ ew2, const float* __restrict__ eb2,
    const float* __restrict__ eg2, const float* __restrict__ ebe2,
    const float* __restrict__ b3,
    float* __restrict__ zbuf, uint32_t* __restrict__ dxp,
    float* __restrict__ bd3g, float* __restrict__ dtb) {
    int tid = threadIdx.x;
    if (blockIdx.x < 4096) {
        // ---------------- pack role ----------------
        int idx = blockIdx.x * 256 + tid;
        if (idx < 160 * 512) {
            int r = idx >> 9, t = idx & 511;
            int j = t >> 1, half = t & 1;
            float a, bb;
            if (r < 32)      { int ip = half * 32 + r;      a = w0[(2*ip)*HFF + j]; bb = w0[(2*ip+1)*HFF + j]; }
            else if (r < 96) { int ip = half * 64 + (r-32); a = w1[(2*ip)*HFF + j]; bb = w1[(2*ip+1)*HFF + j]; }
            else             { int ip = half * 64 + (r-96); a = w2[(2*ip)*HFF + j]; bb = w2[(2*ip+1)*HFF + j]; }
            wcol[idx] = packh2(a, bb);
        }
        if (idx < 32768 * 32) {
            int m = idx >> 5, dd = (idx & 31) * 2;
            int e = 4 * (m >> 9) + (m & 3);
            int h = (m >> 2) & 127;
            const float* row = w3 + (size_t)e * (H * D) + h * D;
            float a = (dd     < D) ? row[dd]     : 0.f;
            float b = (dd + 1 < D) ? row[dd + 1] : 0.f;
            wp[idx] = packh2(a, b);
        }
        return;
    }
    // ---------------- prep role (256 threads) ----------------
    __shared__ float x0[D], hb[H], dxs[NSTEP][D];
    int b = blockIdx.x - 4096;
    if (tid < D) x0[tid] = path[b * S * D + tid];
    __syncthreads();
    if (tid < H) {
        float acc = eb1[tid];
        for (int d = 0; d < D; ++d) acc += x0[d] * ew1[d * H + tid];
        hb[tid] = gelu_exact(acc * (eg1[tid] * BN_SCALE) + ebe1[tid]);
    }
    __syncthreads();
    if (tid < H) {
        float acc = eb2[tid];
        for (int i = 0; i < H; ++i) acc += hb[i] * ew2[i * H + tid];
        zbuf[b * H + tid] = acc * (eg2[tid] * BN_SCALE) + ebe2[tid];
    }
    for (int idx = tid; idx < NSTEP * 32; idx += 256) {
        int s = idx >> 5, j2 = idx & 31;
        uint32_t val = 0;
        if (j2 < DP) {
            float dtv = ts[s + 1] - ts[s];
            int base = b * S * D + s * D + 2 * j2;
            float v0 = (path[base + D] - path[base]) / dtv;
            float v1 = (path[base + D + 1] - path[base + 1]) / dtv;
            dxs[s][2 * j2] = v0; dxs[s][2 * j2 + 1] = v1;
            val = packh2(v0, v1);
        }
        dxp[((size_t)(s * B + b)) * 32 + j2] = val;
    }
    __syncthreads();
    if (tid < H) {
        for (int s = 0; s < NSTEP; ++s) {
            float a = 0.f;
            for (int d = 0; d < D; ++d) a += b3[tid * D + d] * dxs[s][d];
            bd3g[(size_t)(s * B + b) * H + tid] = a;
        }
    }
    if (b == 0 && tid < NSTEP) dtb[tid] = ts[tid + 1] - ts[tid];
}

// ---------------------------------------------------------------------------
// MFMA A-phase (round-9 version, unchanged): LDS-transpose coalesced stores.
// ---------------------------------------------------------------------------
__global__ void __launch_bounds__(256) amm_kernel(
    const uint32_t* __restrict__ wp, const uint32_t* __restrict__ dxp,
    uint32_t* __restrict__ Ach, int s0) {
    __shared__ __align__(16) uint32_t xpose[4][16 * 36];   // 9.2 KB
    int t = threadIdx.x;
    int l = t & 63, wid = t >> 6;
    int mg = (blockIdx.x & 63) * 4 + wid;        // 0..255
    int sg = blockIdx.x >> 6;                    // 0..31
    int lr = l & 15, lk = l >> 4;
    const char* wpB = (const char*)wp;
    const char* dxB = (const char*)dxp + (size_t)s0 * B * 128;
    char* asB = (char*)Ach;
    uint32_t* xp = xpose[wid];
    f16x8 af0[8], af1[8];
#pragma unroll
    for (int mi = 0; mi < 8; ++mi) {
        const f16x8* p = (const f16x8*)(wpB + ((size_t)(mg * 8 + mi) * 16 + lr) * 128 + lk * 16);
        af0[mi] = p[0]; af1[mi] = p[4];          // d 0..31, d 32..63
    }
#pragma unroll
    for (int si = 0; si < 8; ++si) {
        int q = sg * 128 + si * 16 + lr;         // chunk-local slice (this lane's C col)
#pragma unroll
        for (int mi = 0; mi < 8; ++mi) {
            const f16x8* bp = (const f16x8*)(dxB + (size_t)q * 128 + lk * 16);
            f16x8 b0 = bp[0], b1 = bp[4];
            f32x4 acc = {0.f, 0.f, 0.f, 0.f};
            acc = __builtin_amdgcn_mfma_f32_16x16x32_f16(af0[mi], b0, acc, 0, 0, 0);
            acc = __builtin_amdgcn_mfma_f32_16x16x32_f16(af1[mi], b1, acc, 0, 0, 0);
            uint32_t P0 = packh2(acc[0], acc[1]) + 0x00800080u;
            uint32_t P1 = packh2(acc[2], acc[3]) + 0x00800080u;
            uint32_t Q = __builtin_amdgcn_perm(P1, P0, 0x07050301u);
            xp[lr * 36 + lk + 4 * mi] = Q;
        }
        __syncthreads();
        {
            int qr = l >> 2, seg = l & 3;
            const uint4* src = (const uint4*)(xp + qr * 36 + seg * 8);
            uint4 v0 = src[0], v1 = src[1];
            int qout = sg * 128 + si * 16 + qr;
            char* outB = asB + (size_t)qout * 32768 + mg * 128 + seg * 32;
            *(uint4*)outB = v0;
            *(uint4*)(outB + 16) = v1;
        }
        __syncthreads();
    }
}

// ---------------------------------------------------------------------------
// Scan (per 16-step chunk): frozen r7/r9 main loop (158.6 us, VGPR 120-124,
// no spill; alternatives r1-r4, r6, r8, r10 all regressed/neutral).
// do_att epilogue (last chunk): att ONLY (r12's dec-fold cost +30 us —
// 8-wave tail had no TLP to hide the dec load chains; dec is a separate
// 5120-block dispatch again).  Epilogue keeps r12's verified fixes:
//  * LDS aliased onto dead ABUF[0] (LDS stays 67584).
//  * rotated quarter reads (ii = i0 + ((i+8g)&31)) — conflict-free
//    (r11's 131072 conflicts were stride-32-dword same-bank reads).
// ---------------------------------------------------------------------------
__global__ void __launch_bounds__(512, 1)
__attribute__((amdgpu_waves_per_eu(2, 8)))
scan_kernel(
    const uint32_t* __restrict__ wcol, const uint32_t* __restrict__ Ach,
    const float* __restrict__ vb0, const float* __restrict__ vg0, const float* __restrict__ vbe0,
    const float* __restrict__ vb1, const float* __restrict__ vg1, const float* __restrict__ vbe1,
    const float* __restrict__ vb2, const float* __restrict__ vg2, const float* __restrict__ vbe2,
    const float* __restrict__ bd3g, const float* __restrict__ dtb,
    float* __restrict__ zbuf, int s0, int do_att,
    const float* __restrict__ wv, const float* __restrict__ bv,
    const float* __restrict__ wo, const float* __restrict__ bo,
    float* __restrict__ att) {
    __shared__ __align__(16) uint32_t ABUF[2][ADW];            // 64 KB
    __shared__ __align__(16) uint32_t zzPd[72];                // half*36 + r
    __shared__ __align__(16) uint32_t yA[136], yB[136], yC[136]; // half*68 + r
    int t = threadIdx.x, b = blockIdx.x;
    int j = t >> 1, half = t & 1;                     // MLP role
    int h = t >> 2, g = t & 3;                        // L3/state role
    int hswz = h ^ (g << 3);                          // swizzled A column
    uint32_t w0h[32], w1h[64], w2h[64];
#pragma unroll
    for (int r = 0; r < 32; ++r) w0h[r] = wcol[r * 512 + t];
#pragma unroll
    for (int r = 0; r < 64; ++r) w1h[r] = wcol[(32 + r) * 512 + t];
#pragma unroll
    for (int r = 0; r < 64; ++r) w2h[r] = wcol[(96 + r) * 512 + t];
    // folded BN: out = gelu(p*cs + co)
    float c0s = vg0[j] * BN_SCALE, c0o = vb0[j] * c0s + vbe0[j];
    float c1s = vg1[j] * BN_SCALE, c1o = vb1[j] * c1s + vbe1[j];
    float c2s = vg2[j] * BN_SCALE, c2o = vb2[j] * c2s + vbe2[j];
    float zf = zbuf[b * H + h];
    // prologue: stage A for local step 0 (swizzled)
    {
        const uint4* Ag = (const uint4*)(Ach + (size_t)b * ADW);
        uint4 a0 = Ag[t], a1 = Ag[512 + t], a2 = Ag[1024 + t], a3 = Ag[1536 + t];
        uint4* Ad = (uint4*)ABUF[0];
        Ad[aswz(t)] = a0; Ad[aswz(512 + t)] = a1;
        Ad[aswz(1024 + t)] = a2; Ad[aswz(1536 + t)] = a3;
    }
    {
        float zhi = __shfl_down(zf, 4, 64);
        if ((t & 7) == 0) {
            int ip = t >> 3;
            zzPd[(ip >> 5) * 36 + (ip & 31)] = packh2(zf, zhi);
        }
    }
    __syncthreads();

    for (int sl = 0; sl < CH; ++sl) {
        int s = s0 + sl;
        float hstep = dtb[s];
        float bd3 = bd3g[(size_t)(s * B + b) * H + h];
        // prefetch next step's A into registers (in flight across the step)
        uint4 pf0, pf1, pf2, pf3;
        {
            int sn = (sl + 1 < CH) ? sl + 1 : sl;
            const uint4* Ag = (const uint4*)(Ach + (size_t)(sn * B + b) * ADW);
            pf0 = Ag[t]; pf1 = Ag[512 + t]; pf2 = Ag[1024 + t]; pf3 = Ag[1536 + t];
        }
        const uint32_t* AL = ABUF[sl & 1];
        float ksum = 0.f, kcur = 0.f;
        for (int r = 0; r < 4; ++r) {
            // ---- L0: 128 -> 256 (half-K per lane, 4 accumulators) ----
            {
                float pa = 0.f, pb = 0.f, pc = 0.f, pd = 0.f;
                const uint4* zq = (const uint4*)(zzPd + half * 36);
#pragma unroll
                for (int u4 = 0; u4 < 8; ++u4) {
                    uint4 zv = zq[u4];
                    pa = fdot2u(w0h[4*u4+0], zv.x, pa); pb = fdot2u(w0h[4*u4+1], zv.y, pb);
                    pc = fdot2u(w0h[4*u4+2], zv.z, pc); pd = fdot2u(w0h[4*u4+3], zv.w, pd);
                }
                float p = (pa + pb) + (pc + pd);
                p += __shfl_xor(p, 1, 64);
                float v = gelu_fast(p * c0s + c0o);
                float vhi = __shfl_down(v, 2, 64);
                if ((t & 3) == 0) {
                    int ip = t >> 2;
                    yA[(ip >> 6) * 68 + (ip & 63)] = packh2(v, vhi);
                }
            }
            __syncthreads();
            // ---- L1: 256 -> 256 (4 accumulators) ----
            {
                float pa = 0.f, pb = 0.f, pc = 0.f, pd = 0.f;
                const uint4* yq = (const uint4*)(yA + half * 68);
#pragma unroll
                for (int u4 = 0; u4 < 16; ++u4) {
                    uint4 yv = yq[u4];
                    pa = fdot2u(w1h[4*u4+0], yv.x, pa); pb = fdot2u(w1h[4*u4+1], yv.y, pb);
                    pc = fdot2u(w1h[4*u4+2], yv.z, pc); pd = fdot2u(w1h[4*u4+3], yv.w, pd);
                }
                float p = (pa + pb) + (pc + pd);
                p += __shfl_xor(p, 1, 64);
                float v = gelu_fast(p * c1s + c1o);
                float vhi = __shfl_down(v, 2, 64);
                if ((t & 3) == 0) {
                    int ip = t >> 2;
                    yB[(ip >> 6) * 68 + (ip & 63)] = packh2(v, vhi);
                }
            }
            __syncthreads();
            // ---- L2: 256 -> 256 (4 accumulators) ----
            {
                float pa = 0.f, pb = 0.f, pc = 0.f, pd = 0.f;
                const uint4* yq = (const uint4*)(yB + half * 68);
#pragma unroll
                for (int u4 = 0; u4 < 16; ++u4) {
                    uint4 yv = yq[u4];
                    pa = fdot2u(w2h[4*u4+0], yv.x, pa); pb = fdot2u(w2h[4*u4+1], yv.y, pb);
                    pc = fdot2u(w2h[4*u4+2], yv.z, pc); pd = fdot2u(w2h[4*u4+3], yv.w, pd);
                }
                float p = (pa + pb) + (pc + pd);
                p += __shfl_xor(p, 1, 64);
                float v = gelu_fast(p * c2s + c2o);
                float vhi = __shfl_down(v, 2, 64);
                if ((t & 3) == 0) {
                    int ip = t >> 2;
                    yC[(ip >> 6) * 68 + (ip & 63)] = packh2(v, vhi);
                }
            }
            __syncthreads();
            // ---- L3 + state (fused): lane (h = t>>2, g = t&3) covers
            //      k-quads g*16..g*16+15; intra-wave reduce over g. ----
            {
                float pA = 0.f, pB = 0.f, pC = 0.f, pD = 0.f;
                int ybase = (g >> 1) * 68 + (g & 1) * 32;
                const uint4* yq = (const uint4*)(yC + ybase);
#pragma unroll
                for (int kk = 0; kk < 8; ++kk) {
                    uint4 yv = yq[kk];
                    int k0 = g * 16 + 2 * kk;
                    uint32_t Qa = AL[k0 * 128 + hswz];
                    uint32_t Qb = AL[(k0 + 1) * 128 + hswz];
                    pA = fdot2u(__builtin_amdgcn_perm(0u, Qa, 0x010C000Cu), yv.x, pA);
                    pB = fdot2u(__builtin_amdgcn_perm(0u, Qa, 0x030C020Cu), yv.y, pB);
                    pC = fdot2u(__builtin_amdgcn_perm(0u, Qb, 0x010C000Cu), yv.z, pC);
                    pD = fdot2u(__builtin_amdgcn_perm(0u, Qb, 0x030C020Cu), yv.w, pD);
                }
                float ptot = (pA + pB) + (pC + pD);
                ptot += __shfl_xor(ptot, 1, 64);
                ptot += __shfl_xor(ptot, 2, 64);
                kcur = bd3 + ptot;                    // redundant across g-lanes
                float wsm = (r == 1 || r == 2) ? 2.f : 1.f;
                ksum += wsm * kcur;
                float zz;
                if (r < 3) {
                    float cin = (r == 2) ? 1.f : 0.5f;
                    zz = zf + cin * hstep * kcur;
                } else {
                    zf += hstep * (1.f / 6.f) * ksum;
                    zz = zf;
                }
                float zhi = __shfl_down(zz, 4, 64);
                if ((t & 7) == 0) {
                    int ip = t >> 3;
                    zzPd[(ip >> 5) * 36 + (ip & 31)] = packh2(zz, zhi);
                }
            }
            if (r == 3) {  // stage prefetched A into the other buffer (swizzled)
                uint4* Ad = (uint4*)ABUF[(sl + 1) & 1];
                Ad[aswz(t)] = pf0; Ad[aswz(512 + t)] = pf1;
                Ad[aswz(1024 + t)] = pf2; Ad[aswz(1536 + t)] = pf3;
            }
            __syncthreads();
        }
    }
    if ((t & 3) == 0) zbuf[b * H + h] = zf;
    if (do_att) {
        // LDS reuse: ABUF[0] is dead after the main loop (final AL=ABUF[1]).
        float* zfl = (float*)ABUF[0];        // [128]
        float* vv  = zfl + 128;              // [128]
        if ((t & 3) == 0) zfl[h] = zf;
        __syncthreads();
        // attended layer 1: vv[h] = bv[h] + sum_i zfl[i]*wv[i*H+h].
        // Rotated quarter iteration -> conflict-free banks.
        {
            float acc = 0.f;
            int i0 = 32 * g;
#pragma unroll 8
            for (int i = 0; i < 32; ++i) {
                int ii = i0 + ((i + 8 * g) & 31);
                acc += zfl[ii] * wv[ii * H + h];
            }
            acc += __shfl_xor(acc, 1, 64);
            acc += __shfl_xor(acc, 2, 64);
            if (g == 0) vv[h] = acc + bv[h];
        }
        __syncthreads();
        // attended layer 2: att[b*H+h] = bo[h] + sum_i vv[i]*wo[i*H+h]
        {
            float acc = 0.f;
            int i0 = 32 * g;
#pragma unroll 8
            for (int i = 0; i < 32; ++i) {
                int ii = i0 + ((i + 8 * g) & 31);
                acc += vv[ii] * wo[ii * H + h];
            }
            acc += __shfl_xor(acc, 1, 64);
            acc += __shfl_xor(acc, 2, 64);
            if (g == 0) att[b * H + h] = acc + bo[h];
        }
    }
}

// ---------------------------------------------------------------------------
// Decoder: one single-wave block per (t, b).  grid = T*B = 5120.
// (Restored from r11 — folding it into the scan tail cost +30 us: 8 waves/CU
// can't hide the 128-iteration load chains that 20 blocks/CU could.)
// ---------------------------------------------------------------------------
__global__ void __launch_bounds__(64) dec_kernel(
    const float* __restrict__ att,
    const float* __restrict__ dw1, const float* __restrict__ db1,
    const float* __restrict__ dw2, const float* __restrict__ db2,
    const float* __restrict__ dw3, const float* __restrict__ db3,
    float* __restrict__ out) {
    int bid = blockIdx.x;
    int t = bid >> 8, b = bid & 255;
    int tid = threadIdx.x;
    __shared__ float al[H], h1l[64];
    al[tid] = att[b * H + tid];
    al[tid + 64] = att[b * H + tid + 64];
    __syncthreads();
    {
        float acc = db1[t * 64 + tid];
#pragma unroll 8
        for (int i = 0; i < H; ++i) acc += al[i] * dw1[t * H * 64 + i * 64 + tid];
        h1l[tid] = gelu_exact(acc);
    }
    __syncthreads();
    float v = 0.f;
    if (tid < 32) {
        float acc = db2[t * 32 + tid];
#pragma unroll 8
        for (int i = 0; i < 64; ++i) acc += h1l[i] * dw2[t * 64 * 32 + i * 32 + tid];
        v = gelu_exact(acc) * dw3[t * 32 + tid];
    }
#pragma unroll
    for (int off = 16; off >= 1; off >>= 1) v += __shfl_down(v, off, 64);
    if (tid == 0) out[b * T + t] = 1.f / (1.f + expf(-(v + db3[t])));
}

// ---------------------------------------------------------------------------
extern "C" void kernel_launch(void* const* d_in, const int* in_sizes, int n_in,
                              void* d_out, int out_size, void* d_ws, size_t ws_size,
                              hipStream_t stream) {
    const float* path = (const float*)d_in[0];
    const float* ts   = (const float*)d_in[1];
    const float* ew1  = (const float*)d_in[2];
    const float* eb1  = (const float*)d_in[3];
    const float* eg1  = (const float*)d_in[4];
    const float* ebe1 = (const float*)d_in[5];
    const float* ew2  = (const float*)d_in[6];
    const float* eb2  = (const float*)d_in[7];
    const float* eg2  = (const float*)d_in[8];
    const float* ebe2 = (const float*)d_in[9];
    const float* vw0  = (const float*)d_in[10];
    const float* vb0  = (const float*)d_in[11];
    const float* vg0  = (const float*)d_in[12];
    const float* vbe0 = (const float*)d_in[13];
    const float* vw1  = (const float*)d_in[14];
    const float* vb1  = (const float*)d_in[15];
    const float* vg1  = (const float*)d_in[16];
    const float* vbe1 = (const float*)d_in[17];
    const float* vw2  = (const float*)d_in[18];
    const float* vb2  = (const float*)d_in[19];
    const float* vg2  = (const float*)d_in[20];
    const float* vbe2 = (const float*)d_in[21];
    const float* vw3  = (const float*)d_in[22];
    const float* vb3  = (const float*)d_in[23];
    const float* wv   = (const float*)d_in[24];
    const float* bv   = (const float*)d_in[25];
    const float* wo   = (const float*)d_in[26];
    const float* bo   = (const float*)d_in[27];
    const float* dw1  = (const float*)d_in[28];
    const float* db1  = (const float*)d_in[29];
    const float* dw2  = (const float*)d_in[30];
    const float* db2  = (const float*)d_in[31];
    const float* dw3  = (const float*)d_in[32];
    const float* db3  = (const float*)d_in[33];

    char* ws = (char*)d_ws;
    size_t off = 0;
    auto take = [&](size_t bytes) { char* p = ws + off; off += (bytes + 255) & ~(size_t)255; return p; };
    uint32_t* Ach   = (uint32_t*)take((size_t)CH * B * ADW * 4);    // 128 MiB
    uint32_t* dxp   = (uint32_t*)take((size_t)NSTEP * B * 32 * 4);  // 1 MiB (padded rows)
    float*    bd3g  = (float*)take((size_t)NSTEP * B * H * 4);      // 4 MiB
    float*    dtb   = (float*)take(NSTEP * 4);
    float*    zbuf  = (float*)take((size_t)B * H * 4);
    float*    att   = (float*)take((size_t)B * H * 4);
    uint32_t* wcol  = (uint32_t*)take((size_t)160 * 512 * 4);       // 320 KB
    uint32_t* wp    = (uint32_t*)take((size_t)32768 * 32 * 4);      // 4 MiB

    packprep_kernel<<<4096 + B, 256, 0, stream>>>(
        vw0, vw1, vw2, vw3, wcol, wp,
        path, ts, ew1, eb1, eg1, ebe1, ew2, eb2, eg2, ebe2, vb3,
        zbuf, dxp, bd3g, dtb);
    for (int c = 0; c < NCH; ++c) {
        amm_kernel<<<2048, 256, 0, stream>>>(wp, dxp, Ach, c * CH);
        scan_kernel<<<B, 512, 0, stream>>>(wcol, Ach,
                                           vb0, vg0, vbe0, vb1, vg1, vbe1, vb2, vg2, vbe2,
                                           bd3g, dtb, zbuf, c * CH,
                                           (c == NCH - 1) ? 1 : 0,
                                           wv, bv, wo, bo, att);
    }
    dec_kernel<<<T * B, 64, 0, stream>>>(att, dw1, db1, dw2, db2, dw3, db3, (float*)d_out);
}